// Round 1
// baseline (605.578 us; speedup 1.0000x reference)
//
#include <hip/hip_runtime.h>
#include <hip/hip_bf16.h>
#include <cstdint>
#include <cstddef>

typedef __bf16 bf16;
typedef __attribute__((ext_vector_type(8))) __bf16 bf16x8;
typedef __attribute__((ext_vector_type(4))) float f32x4;

#define BB 4
#define TT 4096
#define DD 512
#define MM (BB * TT)              // 16384 rows
#define OUT1_OFF ((size_t)MM * DD)

typedef __attribute__((address_space(1))) void as1_void;
typedef __attribute__((address_space(3))) void as3_void;

__device__ __forceinline__ void gl_lds16(const void* g, void* l) {
    __builtin_amdgcn_global_load_lds((as1_void*)(uintptr_t)g,
                                     (as3_void*)(uintptr_t)l, 16, 0, 0);
}

// ---------------------------------------------------------------- transpose
// in: [R][C] f32 row-major -> out: [C][R] bf16 row-major
__global__ void transpose_bf16(const float* __restrict__ in, bf16* __restrict__ out,
                               int R, int C) {
    __shared__ float tile[32][33];
    const int c0 = blockIdx.x * 32, r0 = blockIdx.y * 32;
    const int tx = threadIdx.x, ty = threadIdx.y;
#pragma unroll
    for (int i = 0; i < 32; i += 8)
        tile[ty + i][tx] = in[(size_t)(r0 + ty + i) * C + (c0 + tx)];
    __syncthreads();
#pragma unroll
    for (int i = 0; i < 32; i += 8)
        out[(size_t)(c0 + ty + i) * R + (r0 + tx)] = (bf16)tile[tx][ty + i];
}

__global__ void pack_bias(const float* __restrict__ a, const float* __restrict__ b,
                          const float* __restrict__ c, const float* __restrict__ d,
                          float* __restrict__ o) {
    const int i = blockIdx.x * 256 + threadIdx.x;
    if (i < 2048) {
        const float* s = (i < 512) ? a : (i < 1024) ? b : (i < 1536) ? c : d;
        o[i] = s[i & 511];
    }
}

__global__ void zero_kernel(float* __restrict__ p, int n) {
    const int i = blockIdx.x * 256 + threadIdx.x;
    if (i < n) p[i] = 0.f;
}

// ---------------------------------------------------------------- layernorm
// out_bf16 = LN(X [+ Xadd]) * g + b ; one wave per row of 512
__global__ __launch_bounds__(256) void ln_kernel(
    const float* __restrict__ X, const float* __restrict__ Xadd,
    const float* __restrict__ gw, const float* __restrict__ bw,
    bf16* __restrict__ out) {
    const int row = blockIdx.x * 4 + (threadIdx.x >> 6);
    const int lane = threadIdx.x & 63;
    const float* xr = X + (size_t)row * DD + lane * 8;
    float v[8];
    float4 v0 = *(const float4*)xr;
    float4 v1 = *(const float4*)(xr + 4);
    v[0] = v0.x; v[1] = v0.y; v[2] = v0.z; v[3] = v0.w;
    v[4] = v1.x; v[5] = v1.y; v[6] = v1.z; v[7] = v1.w;
    if (Xadd) {
        const float* ad = Xadd + (size_t)row * DD + lane * 8;
        float4 a0 = *(const float4*)ad;
        float4 a1 = *(const float4*)(ad + 4);
        v[0] += a0.x; v[1] += a0.y; v[2] += a0.z; v[3] += a0.w;
        v[4] += a1.x; v[5] += a1.y; v[6] += a1.z; v[7] += a1.w;
    }
    float s = 0.f, ss = 0.f;
#pragma unroll
    for (int i = 0; i < 8; ++i) { s += v[i]; ss += v[i] * v[i]; }
#pragma unroll
    for (int o = 32; o; o >>= 1) { s += __shfl_down(s, o); ss += __shfl_down(ss, o); }
    s = __shfl(s, 0); ss = __shfl(ss, 0);
    const float mu = s * (1.f / DD);
    const float var = ss * (1.f / DD) - mu * mu;
    const float rstd = rsqrtf(var + 1e-5f);
    bf16x8 o8;
#pragma unroll
    for (int i = 0; i < 8; ++i)
        o8[i] = (bf16)((v[i] - mu) * rstd * gw[lane * 8 + i] + bw[lane * 8 + i]);
    *(bf16x8*)(out + (size_t)row * DD + lane * 8) = o8;
}

// ---------------------------------------------------------------- GEMM (bf16 MFMA)
// C[m][n] = sum_k A[m][k] * Bt[n][k]  (+ bias, + epilogue per MODE)
// MODE 0: f32 out = acc + bias
// MODE 1: bf16 out = gelu(acc + bias)           (exact erf gelu)
// MODE 2: f32 out = acc + bias + add1 + add2    (residual fuse)
template <int MODE>
__global__ __launch_bounds__(256) void gemm_bt(
    const bf16* __restrict__ A, const bf16* __restrict__ Bt,
    const float* __restrict__ bias, void* __restrict__ Cout,
    const float* __restrict__ add1, const float* __restrict__ add2,
    int M, int N, int K) {
    __shared__ bf16 As[128 * 32];
    __shared__ bf16 Bs[128 * 32];
    const int tid = threadIdx.x;
    const int lane = tid & 63;
    const int wv = tid >> 6;
    const int wr = wv >> 1, wc = wv & 1;
    const int nb = N >> 7;
    const int bm = blockIdx.x / nb, bn = blockIdx.x % nb;
    const int m0 = bm << 7, n0 = bn << 7;

    const int srow = tid >> 2;            // staging row within tile
    const int scol = (tid & 3) << 3;      // staging col (elements)
    const bf16* Asrc = A + (size_t)(m0 + srow) * K + scol;
    const bf16* Bsrc = Bt + (size_t)(n0 + srow) * K + scol;
    bf16* AsW = &As[wv * 512];
    bf16* BsW = &Bs[wv * 512];
    const size_t rstep = (size_t)64 * K;

    f32x4 acc[4][4] = {};
    const int lr = lane & 15, lg = lane >> 4;
    const int aoff = (wr * 64 + lr) * 32 + lg * 8;
    const int boff = (wc * 64 + lr) * 32 + lg * 8;

    for (int k0 = 0; k0 < K; k0 += 32) {
        gl_lds16(Asrc + k0,         AsW);
        gl_lds16(Asrc + k0 + rstep, AsW + 2048);
        gl_lds16(Bsrc + k0,         BsW);
        gl_lds16(Bsrc + k0 + rstep, BsW + 2048);
        __syncthreads();
        bf16x8 af[4], bfr[4];
#pragma unroll
        for (int mi = 0; mi < 4; ++mi) af[mi] = *(const bf16x8*)&As[aoff + mi * 16 * 32];
#pragma unroll
        for (int ni = 0; ni < 4; ++ni) bfr[ni] = *(const bf16x8*)&Bs[boff + ni * 16 * 32];
#pragma unroll
        for (int mi = 0; mi < 4; ++mi)
#pragma unroll
            for (int ni = 0; ni < 4; ++ni)
                acc[mi][ni] = __builtin_amdgcn_mfma_f32_16x16x32_bf16(
                    af[mi], bfr[ni], acc[mi][ni], 0, 0, 0);
        __syncthreads();
    }

#pragma unroll
    for (int mi = 0; mi < 4; ++mi) {
#pragma unroll
        for (int ni = 0; ni < 4; ++ni) {
            const int gmb = m0 + wr * 64 + mi * 16 + 4 * lg;
            const int gn = n0 + wc * 64 + ni * 16 + lr;
            const float bia = bias[gn];
#pragma unroll
            for (int i = 0; i < 4; ++i) {
                float v = acc[mi][ni][i] + bia;
                const size_t off = (size_t)(gmb + i) * N + gn;
                if (MODE == 0) {
                    ((float*)Cout)[off] = v;
                } else if (MODE == 1) {
                    const float ge = 0.5f * v * (1.0f + erff(v * 0.70710678118654752f));
                    ((bf16*)Cout)[off] = (bf16)ge;
                } else {
                    ((float*)Cout)[off] = v + add1[off] + add2[off];
                }
            }
        }
    }
}

// ---------------------------------------------------------------- p_scalar
// p_scalar[row] = mean_d sigmoid(lin[row][d]) ; one wave per row
__global__ __launch_bounds__(256) void pscalar_kernel(const float* __restrict__ lin,
                                                      float* __restrict__ ps) {
    const int row = blockIdx.x * 4 + (threadIdx.x >> 6);
    const int lane = threadIdx.x & 63;
    const float* pr = lin + (size_t)row * 2048 + lane * 8;
    float s = 0.f;
#pragma unroll
    for (int i = 0; i < 8; ++i) {
        const float v = pr[i];
        s += 1.f / (1.f + __expf(-v));
    }
#pragma unroll
    for (int o = 32; o; o >>= 1) s += __shfl_down(s, o);
    if (!lane) ps[row] = s * (1.f / 512.f);
}

// ---------------------------------------------------------------- scan
// Faithful 13-iteration shift-1 combine; window property => halo of 13.
// lin row layout: [p_lin | theta | b_re | b_im] each 512 wide.
#define SCT 16
#define SW 29
__global__ __launch_bounds__(256) void scan_kernel(const float* __restrict__ lin,
                                                   float* __restrict__ h_re) {
    const int blk = blockIdx.x;
    const int dh = blk & 1;
    const int tc = (blk >> 1) & 255;
    const int b = blk >> 9;
    const int d = dh * 256 + threadIdx.x;
    const int t0 = tc * SCT;
    float ar[SW], ai[SW], br[SW], bi[SW];
#pragma unroll
    for (int w = 0; w < SW; ++w) {
        const int t = t0 - 13 + w;
        if (t >= 0) {
            const float* pp = lin + ((size_t)(b * TT + t)) * 2048 + d;
            const float pl = pp[0];
            const float th = pp[512];
            const float re = pp[1024];
            const float im = pp[1536];
            const float p = 1.f / (1.f + __expf(-pl));
            const float om = 1.f - p;
            float sn, cs;
            __sincosf(th, &sn, &cs);
            ar[w] = om * cs; ai[w] = om * sn; br[w] = re; bi[w] = im;
        } else {
            ar[w] = 0.f; ai[w] = 0.f; br[w] = 0.f; bi[w] = 0.f;
        }
    }
    const int wmin0 = (t0 == 0) ? 14 : 1;
    for (int it = 1; it <= 13; ++it) {
        const int wlo = (it > wmin0) ? it : wmin0;
#pragma unroll
        for (int w = SW - 1; w >= 1; --w) {
            if (w >= wlo) {
                const float nbr = ar[w] * br[w - 1] - ai[w] * bi[w - 1] + br[w];
                const float nbi = ar[w] * bi[w - 1] + ai[w] * br[w - 1] + bi[w];
                if (it < 13) {
                    const float nar = ar[w] * ar[w - 1] - ai[w] * ai[w - 1];
                    const float nai = ar[w] * ai[w - 1] + ai[w] * ar[w - 1];
                    ar[w] = nar; ai[w] = nai;
                }
                br[w] = nbr; bi[w] = nbi;
            }
        }
    }
    float* op = h_re + ((size_t)(b * TT + t0)) * DD + d;
#pragma unroll
    for (int j = 0; j < SCT; ++j) op[(size_t)j * DD] = br[13 + j];
}

// ---------------------------------------------------------------- h_mean partials
__global__ __launch_bounds__(256) void hmean_kernel(const float* __restrict__ h_re,
                                                    float* __restrict__ hsum) {
    const int blk = blockIdx.x;          // 256 = 4b * 2dh * 32tc
    const int b = blk >> 6;
    const int dh = (blk >> 5) & 1;
    const int tc = blk & 31;
    const int d = dh * 256 + threadIdx.x;
    float s = 0.f;
    const float* p = h_re + ((size_t)(b * TT + tc * 128)) * DD + d;
    for (int t = 0; t < 128; ++t) s += p[(size_t)t * DD];
    atomicAdd(&hsum[b * DD + d], s);
}

// ---------------------------------------------------------------- top-16
__global__ __launch_bounds__(256) void topk_kernel(const float* __restrict__ ps,
                                                   int* __restrict__ idx_out) {
    __shared__ float vals[TT];
    __shared__ float rv[4];
    __shared__ int ri[4];
    const int b = blockIdx.x, tid = threadIdx.x;
    for (int i = tid; i < TT; i += 256) vals[i] = ps[b * TT + i];
    __syncthreads();
    for (int kk = 0; kk < 16; ++kk) {
        float bv = -1e30f; int bi = 0x7fffffff;
        for (int i = tid; i < TT; i += 256) {
            const float v = vals[i];
            if (v > bv || (v == bv && i < bi)) { bv = v; bi = i; }
        }
#pragma unroll
        for (int o = 32; o; o >>= 1) {
            const float ov = __shfl_down(bv, o);
            const int oi = __shfl_down(bi, o);
            if (ov > bv || (ov == bv && oi < bi)) { bv = ov; bi = oi; }
        }
        const int lane = tid & 63, wid = tid >> 6;
        if (!lane) { rv[wid] = bv; ri[wid] = bi; }
        __syncthreads();
        if (!tid) {
            float fbv = rv[0]; int fbi = ri[0];
            for (int w = 1; w < 4; ++w)
                if (rv[w] > fbv || (rv[w] == fbv && ri[w] < fbi)) { fbv = rv[w]; fbi = ri[w]; }
            idx_out[b * 16 + kk] = fbi;
            vals[fbi] = -1e30f;
        }
        __syncthreads();
    }
}

// ---------------------------------------------------------------- keys/values
__global__ __launch_bounds__(256) void kv_kernel(
    const float* __restrict__ h_re, const int* __restrict__ tki,
    const float* __restrict__ Wk, const float* __restrict__ Wkb,
    const float* __restrict__ Wv, const float* __restrict__ Wvb,
    float* __restrict__ keys, float* __restrict__ vals) {
    const int blk = blockIdx.x;
    const int b = blk >> 4, j = blk & 15;
    const int tid = threadIdx.x;
    __shared__ float hrow[512];
    const int row = tki[b * 16 + j];
    for (int i = tid; i < 512; i += 256)
        hrow[i] = h_re[((size_t)(b * TT + row)) * DD + i];
    __syncthreads();
    for (int n = tid; n < 512; n += 256) {
        float sk = Wkb[n], sv = Wvb[n];
        for (int k = 0; k < 512; ++k) {
            const float h = hrow[k];
            sk += h * Wk[(size_t)k * 512 + n];
            sv += h * Wv[(size_t)k * 512 + n];
        }
        keys[((size_t)(b * 16 + j)) * 512 + n] = sk;
        vals[((size_t)(b * 16 + j)) * 512 + n] = sv;
    }
}

// ---------------------------------------------------------------- query/gate/attn/out
__global__ __launch_bounds__(256) void attn_out_kernel(
    const float* __restrict__ hsum, const float* __restrict__ Wq,
    const float* __restrict__ Wqb, const float* __restrict__ gw,
    const float* __restrict__ gb, const float* __restrict__ keys,
    const float* __restrict__ vals, float* __restrict__ out1) {
    const int b = blockIdx.x, tid = threadIdx.x;
    const int lane = tid & 63, wid = tid >> 6;
    __shared__ float hm[512];
    __shared__ float q[512];
    __shared__ float sc[16];
    __shared__ float red[4];
    for (int d0 = tid; d0 < 512; d0 += 256)
        hm[d0] = hsum[b * 512 + d0] * (1.f / 4096.f);
    __syncthreads();
    for (int n = tid; n < 512; n += 256) {
        float s = Wqb[n];
        for (int k = 0; k < 512; ++k) s += hm[k] * Wq[(size_t)k * 512 + n];
        q[n] = s;
    }
    float gp = 0.f;
    for (int k = tid; k < 512; k += 256) gp += hm[k] * gw[k];
#pragma unroll
    for (int o = 32; o; o >>= 1) gp += __shfl_down(gp, o);
    if (!lane) red[wid] = gp;
    __syncthreads();   // q and red ready
    const float g = 1.f / (1.f + __expf(-(red[0] + red[1] + red[2] + red[3] + gb[0])));
    for (int kk = wid; kk < 16; kk += 4) {
        float sp = 0.f;
        const float* kr = keys + ((size_t)(b * 16 + kk)) * 512;
        for (int k2 = lane; k2 < 512; k2 += 64) sp += q[k2] * kr[k2];
#pragma unroll
        for (int o = 32; o; o >>= 1) sp += __shfl_down(sp, o);
        if (!lane) sc[kk] = sp * 0.04419417382415922f;  // 1/sqrt(512)
    }
    __syncthreads();
    float mx = sc[0];
#pragma unroll
    for (int kk = 1; kk < 16; ++kk) mx = fmaxf(mx, sc[kk]);
    float den = 0.f;
    float w16[16];
#pragma unroll
    for (int kk = 0; kk < 16; ++kk) { w16[kk] = __expf(sc[kk] - mx); den += w16[kk]; }
    const float rden = 1.f / den;
    for (int d0 = tid; d0 < 512; d0 += 256) {
        float co = 0.f;
#pragma unroll
        for (int kk = 0; kk < 16; ++kk)
            co += w16[kk] * vals[((size_t)(b * 16 + kk)) * 512 + d0];
        out1[b * 512 + d0] = hm[d0] + g * (co * rden);
    }
}

// ---------------------------------------------------------------- launch
extern "C" void kernel_launch(void* const* d_in, const int* in_sizes, int n_in,
                              void* d_out, int out_size, void* d_ws, size_t ws_size,
                              hipStream_t stream) {
    const float* x    = (const float*)d_in[0];
    const float* ln1g = (const float*)d_in[1];
    const float* ln1b = (const float*)d_in[2];
    const float* ln2g = (const float*)d_in[3];
    const float* ln2b = (const float*)d_in[4];
    const float* Wp_w = (const float*)d_in[5];
    const float* Wp_b = (const float*)d_in[6];
    const float* Wt_w = (const float*)d_in[7];
    const float* Wt_b = (const float*)d_in[8];
    const float* Wr_w = (const float*)d_in[9];
    const float* Wr_b = (const float*)d_in[10];
    const float* Wi_w = (const float*)d_in[11];
    const float* Wi_b = (const float*)d_in[12];
    const float* Wk_w = (const float*)d_in[13];
    const float* Wk_b = (const float*)d_in[14];
    const float* Wv_w = (const float*)d_in[15];
    const float* Wv_b = (const float*)d_in[16];
    const float* Wq_w = (const float*)d_in[17];
    const float* Wq_b = (const float*)d_in[18];
    const float* gw   = (const float*)d_in[19];
    const float* gb   = (const float*)d_in[20];
    const float* f1w  = (const float*)d_in[21];
    const float* f1b  = (const float*)d_in[22];
    const float* f2w  = (const float*)d_in[23];
    const float* f2b  = (const float*)d_in[24];

    char* wsp = (char*)d_ws;
    float* lin = (float*)wsp;                       // [M][2048] f32  (134 MB)
    char* p = wsp + (size_t)134217728;
    bf16* xn = (bf16*)p;     p += 16777216;         // [M][512] bf16
    float* h_re = (float*)p; p += 33554432;         // [M][512] f32
    bf16* hn = (bf16*)p;     p += 16777216;         // [M][512] bf16
    bf16* wcat = (bf16*)p;   p += 2097152;          // [2048][512] bf16 (Bt)
    bf16* f1bt = (bf16*)p;   p += 2097152;          // [2048][512] bf16
    bf16* f2bt = (bf16*)p;   p += 2097152;          // [512][2048] bf16
    float* bcat = (float*)p; p += 8192;             // [2048]
    float* ps = (float*)p;   p += 65536;            // [B][T]
    float* hsum = (float*)p; p += 8192;             // [B][512]
    int* tki = (int*)p;      p += 256;              // [B][16]
    float* keys = (float*)p; p += 131072;           // [B][16][512]
    float* valsb = (float*)p;                       // [B][16][512]
    bf16* act = (bf16*)lin;                         // FFN1 activations overlay lin
    float* out0 = (float*)d_out;
    float* out1 = (float*)d_out + OUT1_OFF;

    dim3 tb(32, 8);
    // weight packing (B^T bf16 layouts)
    transpose_bf16<<<dim3(16, 16), tb, 0, stream>>>(Wp_w, wcat + (size_t)0 * 512 * 512, 512, 512);
    transpose_bf16<<<dim3(16, 16), tb, 0, stream>>>(Wt_w, wcat + (size_t)1 * 512 * 512, 512, 512);
    transpose_bf16<<<dim3(16, 16), tb, 0, stream>>>(Wr_w, wcat + (size_t)2 * 512 * 512, 512, 512);
    transpose_bf16<<<dim3(16, 16), tb, 0, stream>>>(Wi_w, wcat + (size_t)3 * 512 * 512, 512, 512);
    transpose_bf16<<<dim3(64, 16), tb, 0, stream>>>(f1w, f1bt, 512, 2048);
    transpose_bf16<<<dim3(16, 64), tb, 0, stream>>>(f2w, f2bt, 2048, 512);
    pack_bias<<<8, 256, 0, stream>>>(Wp_b, Wt_b, Wr_b, Wi_b, bcat);

    // LN1 -> xn
    ln_kernel<<<4096, 256, 0, stream>>>(x, nullptr, ln1g, ln1b, xn);
    // fused 4-projection GEMM: lin = xn @ [Wp|Wt|Wr|Wi] + bias
    gemm_bt<0><<<2048, 256, 0, stream>>>(xn, wcat, bcat, lin, nullptr, nullptr, MM, 2048, 512);
    // p_scalar rows
    pscalar_kernel<<<4096, 256, 0, stream>>>(lin, ps);
    // windowed 13-iteration scan (transform fused) -> h_re
    scan_kernel<<<2048, 256, 0, stream>>>(lin, h_re);
    // h_mean partial sums
    zero_kernel<<<8, 256, 0, stream>>>(hsum, 2048);
    hmean_kernel<<<256, 256, 0, stream>>>(h_re, hsum);
    // cache path
    topk_kernel<<<4, 256, 0, stream>>>(ps, tki);
    kv_kernel<<<64, 256, 0, stream>>>(h_re, tki, Wk_w, Wk_b, Wv_w, Wv_b, keys, valsb);
    attn_out_kernel<<<4, 256, 0, stream>>>(hsum, Wq_w, Wq_b, gw, gb, keys, valsb, out1);
    // FFN path
    ln_kernel<<<4096, 256, 0, stream>>>(h_re, x, ln2g, ln2b, hn);
    gemm_bt<1><<<2048, 256, 0, stream>>>(hn, f1bt, f1b, act, nullptr, nullptr, MM, 2048, 512);
    gemm_bt<2><<<512, 256, 0, stream>>>(act, f2bt, f2b, out0, h_re, x, MM, 512, 2048);
}

// Round 2
// 492.902 us; speedup vs baseline: 1.2286x; 1.2286x over previous
//
#include <hip/hip_runtime.h>
#include <hip/hip_bf16.h>
#include <cstdint>
#include <cstddef>

typedef __bf16 bf16;
typedef __attribute__((ext_vector_type(8))) __bf16 bf16x8;
typedef __attribute__((ext_vector_type(4))) float f32x4;

#define BB 4
#define TT 4096
#define DD 512
#define MM (BB * TT)              // 16384 rows
#define OUT1_OFF ((size_t)MM * DD)

typedef __attribute__((address_space(1))) void as1_void;
typedef __attribute__((address_space(3))) void as3_void;

__device__ __forceinline__ void gl_lds16(const void* g, void* l) {
    __builtin_amdgcn_global_load_lds((as1_void*)(uintptr_t)g,
                                     (as3_void*)(uintptr_t)l, 16, 0, 0);
}

// ---------------------------------------------------------------- transpose
// in: [R][C] f32 row-major -> out: [C][R] bf16 row-major
__global__ void transpose_bf16(const float* __restrict__ in, bf16* __restrict__ out,
                               int R, int C) {
    __shared__ float tile[32][33];
    const int c0 = blockIdx.x * 32, r0 = blockIdx.y * 32;
    const int tx = threadIdx.x, ty = threadIdx.y;
#pragma unroll
    for (int i = 0; i < 32; i += 8)
        tile[ty + i][tx] = in[(size_t)(r0 + ty + i) * C + (c0 + tx)];
    __syncthreads();
#pragma unroll
    for (int i = 0; i < 32; i += 8)
        out[(size_t)(c0 + ty + i) * R + (r0 + tx)] = (bf16)tile[tx][ty + i];
}

__global__ void pack_bias(const float* __restrict__ a, const float* __restrict__ b,
                          const float* __restrict__ c, const float* __restrict__ d,
                          float* __restrict__ o) {
    const int i = blockIdx.x * 256 + threadIdx.x;
    if (i < 2048) {
        const float* s = (i < 512) ? a : (i < 1024) ? b : (i < 1536) ? c : d;
        o[i] = s[i & 511];
    }
}

__global__ void zero_kernel(float* __restrict__ p, int n) {
    const int i = blockIdx.x * 256 + threadIdx.x;
    if (i < n) p[i] = 0.f;
}

// ---------------------------------------------------------------- layernorm
// out_bf16 = LN(X [+ Xadd]) * g + b ; one wave per row of 512
__global__ __launch_bounds__(256) void ln_kernel(
    const float* __restrict__ X, const float* __restrict__ Xadd,
    const float* __restrict__ gw, const float* __restrict__ bw,
    bf16* __restrict__ out) {
    const int row = blockIdx.x * 4 + (threadIdx.x >> 6);
    const int lane = threadIdx.x & 63;
    const float* xr = X + (size_t)row * DD + lane * 8;
    float v[8];
    float4 v0 = *(const float4*)xr;
    float4 v1 = *(const float4*)(xr + 4);
    v[0] = v0.x; v[1] = v0.y; v[2] = v0.z; v[3] = v0.w;
    v[4] = v1.x; v[5] = v1.y; v[6] = v1.z; v[7] = v1.w;
    if (Xadd) {
        const float* ad = Xadd + (size_t)row * DD + lane * 8;
        float4 a0 = *(const float4*)ad;
        float4 a1 = *(const float4*)(ad + 4);
        v[0] += a0.x; v[1] += a0.y; v[2] += a0.z; v[3] += a0.w;
        v[4] += a1.x; v[5] += a1.y; v[6] += a1.z; v[7] += a1.w;
    }
    float s = 0.f, ss = 0.f;
#pragma unroll
    for (int i = 0; i < 8; ++i) { s += v[i]; ss += v[i] * v[i]; }
#pragma unroll
    for (int o = 32; o; o >>= 1) { s += __shfl_down(s, o); ss += __shfl_down(ss, o); }
    s = __shfl(s, 0); ss = __shfl(ss, 0);
    const float mu = s * (1.f / DD);
    const float var = ss * (1.f / DD) - mu * mu;
    const float rstd = rsqrtf(var + 1e-5f);
    bf16x8 o8;
#pragma unroll
    for (int i = 0; i < 8; ++i)
        o8[i] = (bf16)((v[i] - mu) * rstd * gw[lane * 8 + i] + bw[lane * 8 + i]);
    *(bf16x8*)(out + (size_t)row * DD + lane * 8) = o8;
}

// ---------------------------------------------------------------- GEMM (bf16 MFMA)
// C[m][n] = sum_k A[m][k] * Bt[n][k]  (+ bias, + epilogue per MODE)
// MODE 0: f32 out = acc + bias
// MODE 1: bf16 out = gelu(acc + bias)           (exact erf gelu)
// MODE 2: f32 out = acc + bias + add1 + add2    (residual fuse)
template <int MODE>
__global__ __launch_bounds__(256) void gemm_bt(
    const bf16* __restrict__ A, const bf16* __restrict__ Bt,
    const float* __restrict__ bias, void* __restrict__ Cout,
    const float* __restrict__ add1, const float* __restrict__ add2,
    int M, int N, int K) {
    __shared__ bf16 As[128 * 32];
    __shared__ bf16 Bs[128 * 32];
    const int tid = threadIdx.x;
    const int lane = tid & 63;
    const int wv = tid >> 6;
    const int wr = wv >> 1, wc = wv & 1;
    const int nb = N >> 7;
    const int bm = blockIdx.x / nb, bn = blockIdx.x % nb;
    const int m0 = bm << 7, n0 = bn << 7;

    const int srow = tid >> 2;            // staging row within tile
    const int scol = (tid & 3) << 3;      // staging col (elements)
    const bf16* Asrc = A + (size_t)(m0 + srow) * K + scol;
    const bf16* Bsrc = Bt + (size_t)(n0 + srow) * K + scol;
    bf16* AsW = &As[wv * 512];
    bf16* BsW = &Bs[wv * 512];
    const size_t rstep = (size_t)64 * K;

    f32x4 acc[4][4] = {};
    const int lr = lane & 15, lg = lane >> 4;
    const int aoff = (wr * 64 + lr) * 32 + lg * 8;
    const int boff = (wc * 64 + lr) * 32 + lg * 8;

    for (int k0 = 0; k0 < K; k0 += 32) {
        gl_lds16(Asrc + k0,         AsW);
        gl_lds16(Asrc + k0 + rstep, AsW + 2048);
        gl_lds16(Bsrc + k0,         BsW);
        gl_lds16(Bsrc + k0 + rstep, BsW + 2048);
        __syncthreads();
        bf16x8 af[4], bfr[4];
#pragma unroll
        for (int mi = 0; mi < 4; ++mi) af[mi] = *(const bf16x8*)&As[aoff + mi * 16 * 32];
#pragma unroll
        for (int ni = 0; ni < 4; ++ni) bfr[ni] = *(const bf16x8*)&Bs[boff + ni * 16 * 32];
#pragma unroll
        for (int mi = 0; mi < 4; ++mi)
#pragma unroll
            for (int ni = 0; ni < 4; ++ni)
                acc[mi][ni] = __builtin_amdgcn_mfma_f32_16x16x32_bf16(
                    af[mi], bfr[ni], acc[mi][ni], 0, 0, 0);
        __syncthreads();
    }

#pragma unroll
    for (int mi = 0; mi < 4; ++mi) {
#pragma unroll
        for (int ni = 0; ni < 4; ++ni) {
            const int gmb = m0 + wr * 64 + mi * 16 + 4 * lg;
            const int gn = n0 + wc * 64 + ni * 16 + lr;
            const float bia = bias[gn];
#pragma unroll
            for (int i = 0; i < 4; ++i) {
                float v = acc[mi][ni][i] + bia;
                const size_t off = (size_t)(gmb + i) * N + gn;
                if (MODE == 0) {
                    ((float*)Cout)[off] = v;
                } else if (MODE == 1) {
                    const float ge = 0.5f * v * (1.0f + erff(v * 0.70710678118654752f));
                    ((bf16*)Cout)[off] = (bf16)ge;
                } else {
                    ((float*)Cout)[off] = v + add1[off] + add2[off];
                }
            }
        }
    }
}

// ---------------------------------------------------------------- p_scalar
// p_scalar[row] = mean_d sigmoid(lin[row][d]) ; one wave per row
__global__ __launch_bounds__(256) void pscalar_kernel(const float* __restrict__ lin,
                                                      float* __restrict__ ps) {
    const int row = blockIdx.x * 4 + (threadIdx.x >> 6);
    const int lane = threadIdx.x & 63;
    const float* pr = lin + (size_t)row * 2048 + lane * 8;
    float s = 0.f;
#pragma unroll
    for (int i = 0; i < 8; ++i) {
        const float v = pr[i];
        s += 1.f / (1.f + __expf(-v));
    }
#pragma unroll
    for (int o = 32; o; o >>= 1) s += __shfl_down(s, o);
    if (!lane) ps[row] = s * (1.f / 512.f);
}

// ---------------------------------------------------------------- scan
// Faithful 13-iteration shift-1 combine computed as a 13-stage pipeline DP:
// stream over t carrying prev[k] = e_k[t-1] (k=0..12); each position costs
// exactly 13 combines. Warm-up of 13 steps validates all levels (level k at
// position t is valid iff t-k >= t_start). t=0 is frozen by the mask: all
// levels init to e_0[0].
// lin row layout: [p_lin | theta | b_re | b_im] each 512 wide.
#define SCL 32   // outputs per thread
__global__ __launch_bounds__(256) void scan_kernel(const float* __restrict__ lin,
                                                   float* __restrict__ h_re) {
    const int blk = blockIdx.x;
    const int dh = blk & 1;
    const int tc = (blk >> 1) & 127;
    const int b = blk >> 8;
    const int d = dh * 256 + threadIdx.x;
    const int t0 = tc * SCL;

    float par[13], pai[13], pbr[13], pbi[13];
#pragma unroll
    for (int k = 0; k < 13; ++k) { par[k] = 0.f; pai[k] = 0.f; pbr[k] = 0.f; pbi[k] = 0.f; }

    const int warm = (tc == 0) ? 0 : 13;
    const float* pin = lin + ((size_t)(b * TT + t0 - warm)) * 2048 + d;
    float* pout = h_re + ((size_t)(b * TT + t0)) * DD + d;

    // warm-up (no stores); tc==0 skips (warm=0)
    for (int s = 0; s < warm; ++s) {
        const float pl = pin[0];
        const float th = pin[512];
        const float re = pin[1024];
        const float im = pin[1536];
        pin += 2048;
        const float om = 1.f - 1.f / (1.f + __expf(-pl));
        float sn, cs; __sincosf(th, &sn, &cs);
        float car = om * cs, cai = om * sn, cbr = re, cbi = im;
#pragma unroll
        for (int k = 0; k < 13; ++k) {
            const float tar = par[k], tai = pai[k], tbr = pbr[k], tbi = pbi[k];
            par[k] = car; pai[k] = cai; pbr[k] = cbr; pbi[k] = cbi;
            const float nbr = car * tbr - cai * tbi + cbr;
            const float nbi = car * tbi + cai * tbr + cbi;
            if (k < 12) {
                const float nar = car * tar - cai * tai;
                const float nai = car * tai + cai * tar;
                car = nar; cai = nai;
            }
            cbr = nbr; cbi = nbi;
        }
    }

    // main loop: SCL stored outputs
#pragma unroll 2
    for (int s = 0; s < SCL; ++s) {
        const int t = t0 + s;
        const float pl = pin[0];
        const float th = pin[512];
        const float re = pin[1024];
        const float im = pin[1536];
        pin += 2048;
        const float om = 1.f - 1.f / (1.f + __expf(-pl));
        float sn, cs; __sincosf(th, &sn, &cs);
        float car = om * cs, cai = om * sn, cbr = re, cbi = im;
        if (t == 0) {
            // masked position: frozen at e_0[0]; seed all pipeline levels
#pragma unroll
            for (int k = 0; k < 13; ++k) { par[k] = car; pai[k] = cai; pbr[k] = cbr; pbi[k] = cbi; }
        } else {
#pragma unroll
            for (int k = 0; k < 13; ++k) {
                const float tar = par[k], tai = pai[k], tbr = pbr[k], tbi = pbi[k];
                par[k] = car; pai[k] = cai; pbr[k] = cbr; pbi[k] = cbi;
                const float nbr = car * tbr - cai * tbi + cbr;
                const float nbi = car * tbi + cai * tbr + cbi;
                if (k < 12) {
                    const float nar = car * tar - cai * tai;
                    const float nai = car * tai + cai * tar;
                    car = nar; cai = nai;
                }
                cbr = nbr; cbi = nbi;
            }
        }
        pout[(size_t)s * DD] = cbr;
    }
}

// ---------------------------------------------------------------- h_mean partials
__global__ __launch_bounds__(256) void hmean_kernel(const float* __restrict__ h_re,
                                                    float* __restrict__ hsum) {
    const int blk = blockIdx.x;          // 256 = 4b * 2dh * 32tc
    const int b = blk >> 6;
    const int dh = (blk >> 5) & 1;
    const int tc = blk & 31;
    const int d = dh * 256 + threadIdx.x;
    float s = 0.f;
    const float* p = h_re + ((size_t)(b * TT + tc * 128)) * DD + d;
    for (int t = 0; t < 128; ++t) s += p[(size_t)t * DD];
    atomicAdd(&hsum[b * DD + d], s);
}

// ---------------------------------------------------------------- top-16
__global__ __launch_bounds__(256) void topk_kernel(const float* __restrict__ ps,
                                                   int* __restrict__ idx_out) {
    __shared__ float vals[TT];
    __shared__ float rv[4];
    __shared__ int ri[4];
    const int b = blockIdx.x, tid = threadIdx.x;
    for (int i = tid; i < TT; i += 256) vals[i] = ps[b * TT + i];
    __syncthreads();
    for (int kk = 0; kk < 16; ++kk) {
        float bv = -1e30f; int bi = 0x7fffffff;
        for (int i = tid; i < TT; i += 256) {
            const float v = vals[i];
            if (v > bv || (v == bv && i < bi)) { bv = v; bi = i; }
        }
#pragma unroll
        for (int o = 32; o; o >>= 1) {
            const float ov = __shfl_down(bv, o);
            const int oi = __shfl_down(bi, o);
            if (ov > bv || (ov == bv && oi < bi)) { bv = ov; bi = oi; }
        }
        const int lane = tid & 63, wid = tid >> 6;
        if (!lane) { rv[wid] = bv; ri[wid] = bi; }
        __syncthreads();
        if (!tid) {
            float fbv = rv[0]; int fbi = ri[0];
            for (int w = 1; w < 4; ++w)
                if (rv[w] > fbv || (rv[w] == fbv && ri[w] < fbi)) { fbv = rv[w]; fbi = ri[w]; }
            idx_out[b * 16 + kk] = fbi;
            vals[fbi] = -1e30f;
        }
        __syncthreads();
    }
}

// ---------------------------------------------------------------- keys/values
__global__ __launch_bounds__(256) void kv_kernel(
    const float* __restrict__ h_re, const int* __restrict__ tki,
    const float* __restrict__ Wk, const float* __restrict__ Wkb,
    const float* __restrict__ Wv, const float* __restrict__ Wvb,
    float* __restrict__ keys, float* __restrict__ vals) {
    const int blk = blockIdx.x;
    const int b = blk >> 4, j = blk & 15;
    const int tid = threadIdx.x;
    __shared__ float hrow[512];
    const int row = tki[b * 16 + j];
    for (int i = tid; i < 512; i += 256)
        hrow[i] = h_re[((size_t)(b * TT + row)) * DD + i];
    __syncthreads();
    for (int n = tid; n < 512; n += 256) {
        float sk = Wkb[n], sv = Wvb[n];
        for (int k = 0; k < 512; ++k) {
            const float h = hrow[k];
            sk += h * Wk[(size_t)k * 512 + n];
            sv += h * Wv[(size_t)k * 512 + n];
        }
        keys[((size_t)(b * 16 + j)) * 512 + n] = sk;
        vals[((size_t)(b * 16 + j)) * 512 + n] = sv;
    }
}

// ---------------------------------------------------------------- query/gate/attn/out
__global__ __launch_bounds__(256) void attn_out_kernel(
    const float* __restrict__ hsum, const float* __restrict__ Wq,
    const float* __restrict__ Wqb, const float* __restrict__ gw,
    const float* __restrict__ gb, const float* __restrict__ keys,
    const float* __restrict__ vals, float* __restrict__ out1) {
    const int b = blockIdx.x, tid = threadIdx.x;
    const int lane = tid & 63, wid = tid >> 6;
    __shared__ float hm[512];
    __shared__ float q[512];
    __shared__ float sc[16];
    __shared__ float red[4];
    for (int d0 = tid; d0 < 512; d0 += 256)
        hm[d0] = hsum[b * 512 + d0] * (1.f / 4096.f);
    __syncthreads();
    for (int n = tid; n < 512; n += 256) {
        float s = Wqb[n];
        for (int k = 0; k < 512; ++k) s += hm[k] * Wq[(size_t)k * 512 + n];
        q[n] = s;
    }
    float gp = 0.f;
    for (int k = tid; k < 512; k += 256) gp += hm[k] * gw[k];
#pragma unroll
    for (int o = 32; o; o >>= 1) gp += __shfl_down(gp, o);
    if (!lane) red[wid] = gp;
    __syncthreads();   // q and red ready
    const float g = 1.f / (1.f + __expf(-(red[0] + red[1] + red[2] + red[3] + gb[0])));
    for (int kk = wid; kk < 16; kk += 4) {
        float sp = 0.f;
        const float* kr = keys + ((size_t)(b * 16 + kk)) * 512;
        for (int k2 = lane; k2 < 512; k2 += 64) sp += q[k2] * kr[k2];
#pragma unroll
        for (int o = 32; o; o >>= 1) sp += __shfl_down(sp, o);
        if (!lane) sc[kk] = sp * 0.04419417382415922f;  // 1/sqrt(512)
    }
    __syncthreads();
    float mx = sc[0];
#pragma unroll
    for (int kk = 1; kk < 16; ++kk) mx = fmaxf(mx, sc[kk]);
    float den = 0.f;
    float w16[16];
#pragma unroll
    for (int kk = 0; kk < 16; ++kk) { w16[kk] = __expf(sc[kk] - mx); den += w16[kk]; }
    const float rden = 1.f / den;
    for (int d0 = tid; d0 < 512; d0 += 256) {
        float co = 0.f;
#pragma unroll
        for (int kk = 0; kk < 16; ++kk)
            co += w16[kk] * vals[((size_t)(b * 16 + kk)) * 512 + d0];
        out1[b * 512 + d0] = hm[d0] + g * (co * rden);
    }
}

// ---------------------------------------------------------------- launch
extern "C" void kernel_launch(void* const* d_in, const int* in_sizes, int n_in,
                              void* d_out, int out_size, void* d_ws, size_t ws_size,
                              hipStream_t stream) {
    const float* x    = (const float*)d_in[0];
    const float* ln1g = (const float*)d_in[1];
    const float* ln1b = (const float*)d_in[2];
    const float* ln2g = (const float*)d_in[3];
    const float* ln2b = (const float*)d_in[4];
    const float* Wp_w = (const float*)d_in[5];
    const float* Wp_b = (const float*)d_in[6];
    const float* Wt_w = (const float*)d_in[7];
    const float* Wt_b = (const float*)d_in[8];
    const float* Wr_w = (const float*)d_in[9];
    const float* Wr_b = (const float*)d_in[10];
    const float* Wi_w = (const float*)d_in[11];
    const float* Wi_b = (const float*)d_in[12];
    const float* Wk_w = (const float*)d_in[13];
    const float* Wk_b = (const float*)d_in[14];
    const float* Wv_w = (const float*)d_in[15];
    const float* Wv_b = (const float*)d_in[16];
    const float* Wq_w = (const float*)d_in[17];
    const float* Wq_b = (const float*)d_in[18];
    const float* gw   = (const float*)d_in[19];
    const float* gb   = (const float*)d_in[20];
    const float* f1w  = (const float*)d_in[21];
    const float* f1b  = (const float*)d_in[22];
    const float* f2w  = (const float*)d_in[23];
    const float* f2b  = (const float*)d_in[24];

    char* wsp = (char*)d_ws;
    float* lin = (float*)wsp;                       // [M][2048] f32  (134 MB)
    char* p = wsp + (size_t)134217728;
    bf16* xn = (bf16*)p;     p += 16777216;         // [M][512] bf16
    float* h_re = (float*)p; p += 33554432;         // [M][512] f32
    bf16* hn = (bf16*)p;     p += 16777216;         // [M][512] bf16
    bf16* wcat = (bf16*)p;   p += 2097152;          // [2048][512] bf16 (Bt)
    bf16* f1bt = (bf16*)p;   p += 2097152;          // [2048][512] bf16
    bf16* f2bt = (bf16*)p;   p += 2097152;          // [512][2048] bf16
    float* bcat = (float*)p; p += 8192;             // [2048]
    float* ps = (float*)p;   p += 65536;            // [B][T]
    float* hsum = (float*)p; p += 8192;             // [B][512]
    int* tki = (int*)p;      p += 256;              // [B][16]
    float* keys = (float*)p; p += 131072;           // [B][16][512]
    float* valsb = (float*)p;                       // [B][16][512]
    bf16* act = (bf16*)lin;                         // FFN1 activations overlay lin
    float* out0 = (float*)d_out;
    float* out1 = (float*)d_out + OUT1_OFF;

    dim3 tb(32, 8);
    // weight packing (B^T bf16 layouts)
    transpose_bf16<<<dim3(16, 16), tb, 0, stream>>>(Wp_w, wcat + (size_t)0 * 512 * 512, 512, 512);
    transpose_bf16<<<dim3(16, 16), tb, 0, stream>>>(Wt_w, wcat + (size_t)1 * 512 * 512, 512, 512);
    transpose_bf16<<<dim3(16, 16), tb, 0, stream>>>(Wr_w, wcat + (size_t)2 * 512 * 512, 512, 512);
    transpose_bf16<<<dim3(16, 16), tb, 0, stream>>>(Wi_w, wcat + (size_t)3 * 512 * 512, 512, 512);
    transpose_bf16<<<dim3(64, 16), tb, 0, stream>>>(f1w, f1bt, 512, 2048);
    transpose_bf16<<<dim3(16, 64), tb, 0, stream>>>(f2w, f2bt, 2048, 512);
    pack_bias<<<8, 256, 0, stream>>>(Wp_b, Wt_b, Wr_b, Wi_b, bcat);

    // LN1 -> xn
    ln_kernel<<<4096, 256, 0, stream>>>(x, nullptr, ln1g, ln1b, xn);
    // fused 4-projection GEMM: lin = xn @ [Wp|Wt|Wr|Wi] + bias
    gemm_bt<0><<<2048, 256, 0, stream>>>(xn, wcat, bcat, lin, nullptr, nullptr, MM, 2048, 512);
    // p_scalar rows
    pscalar_kernel<<<4096, 256, 0, stream>>>(lin, ps);
    // 13-stage pipeline scan (transform fused) -> h_re
    scan_kernel<<<1024, 256, 0, stream>>>(lin, h_re);
    // h_mean partial sums
    zero_kernel<<<8, 256, 0, stream>>>(hsum, 2048);
    hmean_kernel<<<256, 256, 0, stream>>>(h_re, hsum);
    // cache path
    topk_kernel<<<4, 256, 0, stream>>>(ps, tki);
    kv_kernel<<<64, 256, 0, stream>>>(h_re, tki, Wk_w, Wk_b, Wv_w, Wv_b, keys, valsb);
    attn_out_kernel<<<4, 256, 0, stream>>>(hsum, Wq_w, Wq_b, gw, gb, keys, valsb, out1);
    // FFN path
    ln_kernel<<<4096, 256, 0, stream>>>(h_re, x, ln2g, ln2b, hn);
    gemm_bt<1><<<2048, 256, 0, stream>>>(hn, f1bt, f1b, act, nullptr, nullptr, MM, 2048, 512);
    gemm_bt<2><<<512, 256, 0, stream>>>(act, f2bt, f2b, out0, h_re, x, MM, 512, 2048);
}

// Round 3
// 464.977 us; speedup vs baseline: 1.3024x; 1.0601x over previous
//
#include <hip/hip_runtime.h>
#include <hip/hip_bf16.h>
#include <cstdint>
#include <cstddef>

typedef __bf16 bf16;
typedef __attribute__((ext_vector_type(8))) __bf16 bf16x8;
typedef __attribute__((ext_vector_type(4))) float f32x4;

#define BB 4
#define TT 4096
#define DD 512
#define MM (BB * TT)              // 16384 rows
#define OUT1_OFF ((size_t)MM * DD)

typedef __attribute__((address_space(1))) void as1_void;
typedef __attribute__((address_space(3))) void as3_void;

__device__ __forceinline__ void gl_lds16(const void* g, void* l) {
    __builtin_amdgcn_global_load_lds((as1_void*)(uintptr_t)g,
                                     (as3_void*)(uintptr_t)l, 16, 0, 0);
}

// ---------------------------------------------------------------- transpose
// in: [R][C] f32 row-major -> out: [C][R] bf16 row-major
__global__ void transpose_bf16(const float* __restrict__ in, bf16* __restrict__ out,
                               int R, int C) {
    __shared__ float tile[32][33];
    const int c0 = blockIdx.x * 32, r0 = blockIdx.y * 32;
    const int tx = threadIdx.x, ty = threadIdx.y;
#pragma unroll
    for (int i = 0; i < 32; i += 8)
        tile[ty + i][tx] = in[(size_t)(r0 + ty + i) * C + (c0 + tx)];
    __syncthreads();
#pragma unroll
    for (int i = 0; i < 32; i += 8)
        out[(size_t)(c0 + ty + i) * R + (r0 + tx)] = (bf16)tile[tx][ty + i];
}

__global__ void pack_bias(const float* __restrict__ a, const float* __restrict__ b,
                          const float* __restrict__ c, const float* __restrict__ d,
                          float* __restrict__ o) {
    const int i = blockIdx.x * 256 + threadIdx.x;
    if (i < 2048) {
        const float* s = (i < 512) ? a : (i < 1024) ? b : (i < 1536) ? c : d;
        o[i] = s[i & 511];
    }
}

__global__ void zero_kernel(float* __restrict__ p, int n) {
    const int i = blockIdx.x * 256 + threadIdx.x;
    if (i < n) p[i] = 0.f;
}

// ---------------------------------------------------------------- layernorm
// out_bf16 = LN(X [+ Xadd]) * g + b ; one wave per row of 512
__global__ __launch_bounds__(256) void ln_kernel(
    const float* __restrict__ X, const float* __restrict__ Xadd,
    const float* __restrict__ gw, const float* __restrict__ bw,
    bf16* __restrict__ out) {
    const int row = blockIdx.x * 4 + (threadIdx.x >> 6);
    const int lane = threadIdx.x & 63;
    const float* xr = X + (size_t)row * DD + lane * 8;
    float v[8];
    float4 v0 = *(const float4*)xr;
    float4 v1 = *(const float4*)(xr + 4);
    v[0] = v0.x; v[1] = v0.y; v[2] = v0.z; v[3] = v0.w;
    v[4] = v1.x; v[5] = v1.y; v[6] = v1.z; v[7] = v1.w;
    if (Xadd) {
        const float* ad = Xadd + (size_t)row * DD + lane * 8;
        float4 a0 = *(const float4*)ad;
        float4 a1 = *(const float4*)(ad + 4);
        v[0] += a0.x; v[1] += a0.y; v[2] += a0.z; v[3] += a0.w;
        v[4] += a1.x; v[5] += a1.y; v[6] += a1.z; v[7] += a1.w;
    }
    float s = 0.f, ss = 0.f;
#pragma unroll
    for (int i = 0; i < 8; ++i) { s += v[i]; ss += v[i] * v[i]; }
#pragma unroll
    for (int o = 32; o; o >>= 1) { s += __shfl_down(s, o); ss += __shfl_down(ss, o); }
    s = __shfl(s, 0); ss = __shfl(ss, 0);
    const float mu = s * (1.f / DD);
    const float var = ss * (1.f / DD) - mu * mu;
    const float rstd = rsqrtf(var + 1e-5f);
    bf16x8 o8;
#pragma unroll
    for (int i = 0; i < 8; ++i)
        o8[i] = (bf16)((v[i] - mu) * rstd * gw[lane * 8 + i] + bw[lane * 8 + i]);
    *(bf16x8*)(out + (size_t)row * DD + lane * 8) = o8;
}

// ---------------------------------------------------------------- GEMM (bf16 MFMA)
// 2-phase double-buffered pipeline (T3-minimum): STAGE(t+1) issued before
// compute(t); one __syncthreads per K-step (its vmcnt/lgkmcnt drain covers
// both the prefetch completion and the read-before-overwrite hazard).
// C[m][n] = sum_k A[m][k] * Bt[n][k]  (+ bias, + epilogue per MODE)
// MODE 0: f32 out = acc + bias
// MODE 1: bf16 out = gelu(acc + bias)           (exact erf gelu)
// MODE 2: f32 out = acc + bias + add1 + add2    (residual fuse)
template <int MODE>
__global__ __launch_bounds__(256) void gemm_bt(
    const bf16* __restrict__ A, const bf16* __restrict__ Bt,
    const float* __restrict__ bias, void* __restrict__ Cout,
    const float* __restrict__ add1, const float* __restrict__ add2,
    int M, int N, int K) {
    __shared__ bf16 As[2][128 * 32];
    __shared__ bf16 Bs[2][128 * 32];
    const int tid = threadIdx.x;
    const int lane = tid & 63;
    const int wv = tid >> 6;
    const int wr = wv >> 1, wc = wv & 1;
    const int nb = N >> 7;
    // T1: bijective XCD swizzle (all grids here are multiples of 8)
    const int nwg = gridDim.x;
    const int cpx = nwg >> 3;
    const int bx = ((nwg & 7) == 0) ? ((blockIdx.x & 7) * cpx + (blockIdx.x >> 3))
                                    : blockIdx.x;
    const int bm = bx / nb, bn = bx % nb;
    const int m0 = bm << 7, n0 = bn << 7;

    const int srow = tid >> 2;            // staging row within tile
    const int scol = (tid & 3) << 3;      // staging col (elements)
    const bf16* Asrc = A + (size_t)(m0 + srow) * K + scol;
    const bf16* Bsrc = Bt + (size_t)(n0 + srow) * K + scol;
    const size_t rstep = (size_t)64 * K;
    const int ldsw = wv * 512;            // per-wave LDS staging base (elements)

    f32x4 acc[4][4] = {};
    const int lr = lane & 15, lg = lane >> 4;
    const int aoff = (wr * 64 + lr) * 32 + lg * 8;
    const int boff = (wc * 64 + lr) * 32 + lg * 8;

#define STAGE(buf, k0)                                                  \
    do {                                                                \
        gl_lds16(Asrc + (k0),         &As[buf][ldsw]);                  \
        gl_lds16(Asrc + (k0) + rstep, &As[buf][ldsw + 2048]);           \
        gl_lds16(Bsrc + (k0),         &Bs[buf][ldsw]);                  \
        gl_lds16(Bsrc + (k0) + rstep, &Bs[buf][ldsw + 2048]);           \
    } while (0)

    const int NT = K >> 5;
    STAGE(0, 0);
    __syncthreads();
    int cur = 0;
    for (int t = 0; t < NT - 1; ++t) {
        STAGE(cur ^ 1, (t + 1) << 5);      // prefetch next tile (in flight across compute)
        bf16x8 af[4], bfr[4];
#pragma unroll
        for (int mi = 0; mi < 4; ++mi) af[mi] = *(const bf16x8*)&As[cur][aoff + mi * 16 * 32];
#pragma unroll
        for (int ni = 0; ni < 4; ++ni) bfr[ni] = *(const bf16x8*)&Bs[cur][boff + ni * 16 * 32];
#pragma unroll
        for (int mi = 0; mi < 4; ++mi)
#pragma unroll
            for (int ni = 0; ni < 4; ++ni)
                acc[mi][ni] = __builtin_amdgcn_mfma_f32_16x16x32_bf16(
                    af[mi], bfr[ni], acc[mi][ni], 0, 0, 0);
        __syncthreads();                   // drains prefetch + guards buffer reuse
        cur ^= 1;
    }
    {   // last tile: no prefetch, no trailing barrier
        bf16x8 af[4], bfr[4];
#pragma unroll
        for (int mi = 0; mi < 4; ++mi) af[mi] = *(const bf16x8*)&As[cur][aoff + mi * 16 * 32];
#pragma unroll
        for (int ni = 0; ni < 4; ++ni) bfr[ni] = *(const bf16x8*)&Bs[cur][boff + ni * 16 * 32];
#pragma unroll
        for (int mi = 0; mi < 4; ++mi)
#pragma unroll
            for (int ni = 0; ni < 4; ++ni)
                acc[mi][ni] = __builtin_amdgcn_mfma_f32_16x16x32_bf16(
                    af[mi], bfr[ni], acc[mi][ni], 0, 0, 0);
    }
#undef STAGE

#pragma unroll
    for (int mi = 0; mi < 4; ++mi) {
#pragma unroll
        for (int ni = 0; ni < 4; ++ni) {
            const int gmb = m0 + wr * 64 + mi * 16 + 4 * lg;
            const int gn = n0 + wc * 64 + ni * 16 + lr;
            const float bia = bias[gn];
#pragma unroll
            for (int i = 0; i < 4; ++i) {
                float v = acc[mi][ni][i] + bia;
                const size_t off = (size_t)(gmb + i) * N + gn;
                if (MODE == 0) {
                    ((float*)Cout)[off] = v;
                } else if (MODE == 1) {
                    const float ge = 0.5f * v * (1.0f + erff(v * 0.70710678118654752f));
                    ((bf16*)Cout)[off] = (bf16)ge;
                } else {
                    ((float*)Cout)[off] = v + add1[off] + add2[off];
                }
            }
        }
    }
}

// ---------------------------------------------------------------- p_scalar
// p_scalar[row] = mean_d sigmoid(lin[row][d]) ; one wave per row
__global__ __launch_bounds__(256) void pscalar_kernel(const float* __restrict__ lin,
                                                      float* __restrict__ ps) {
    const int row = blockIdx.x * 4 + (threadIdx.x >> 6);
    const int lane = threadIdx.x & 63;
    const float* pr = lin + (size_t)row * 2048 + lane * 8;
    float s = 0.f;
#pragma unroll
    for (int i = 0; i < 8; ++i) {
        const float v = pr[i];
        s += 1.f / (1.f + __expf(-v));
    }
#pragma unroll
    for (int o = 32; o; o >>= 1) s += __shfl_down(s, o);
    if (!lane) ps[row] = s * (1.f / 512.f);
}

// ---------------------------------------------------------------- scan
// Faithful 13-iteration shift-1 combine computed as a 13-stage pipeline DP:
// stream over t carrying prev[k] = e_k[t-1] (k=0..12); each position costs
// exactly 13 combines. Warm-up of 13 steps validates all levels (level k at
// position t is valid iff t-k >= t_start). t=0 is frozen by the mask: all
// levels init to e_0[0].
// lin row layout: [p_lin | theta | b_re | b_im] each 512 wide.
#define SCL 32   // outputs per thread
__global__ __launch_bounds__(256) void scan_kernel(const float* __restrict__ lin,
                                                   float* __restrict__ h_re) {
    const int blk = blockIdx.x;
    const int dh = blk & 1;
    const int tc = (blk >> 1) & 127;
    const int b = blk >> 8;
    const int d = dh * 256 + threadIdx.x;
    const int t0 = tc * SCL;

    float par[13], pai[13], pbr[13], pbi[13];
#pragma unroll
    for (int k = 0; k < 13; ++k) { par[k] = 0.f; pai[k] = 0.f; pbr[k] = 0.f; pbi[k] = 0.f; }

    const int warm = (tc == 0) ? 0 : 13;
    const float* pin = lin + ((size_t)(b * TT + t0 - warm)) * 2048 + d;
    float* pout = h_re + ((size_t)(b * TT + t0)) * DD + d;

    // warm-up (no stores); tc==0 skips (warm=0)
    for (int s = 0; s < warm; ++s) {
        const float pl = pin[0];
        const float th = pin[512];
        const float re = pin[1024];
        const float im = pin[1536];
        pin += 2048;
        const float om = 1.f - 1.f / (1.f + __expf(-pl));
        float sn, cs; __sincosf(th, &sn, &cs);
        float car = om * cs, cai = om * sn, cbr = re, cbi = im;
#pragma unroll
        for (int k = 0; k < 13; ++k) {
            const float tar = par[k], tai = pai[k], tbr = pbr[k], tbi = pbi[k];
            par[k] = car; pai[k] = cai; pbr[k] = cbr; pbi[k] = cbi;
            const float nbr = car * tbr - cai * tbi + cbr;
            const float nbi = car * tbi + cai * tbr + cbi;
            if (k < 12) {
                const float nar = car * tar - cai * tai;
                const float nai = car * tai + cai * tar;
                car = nar; cai = nai;
            }
            cbr = nbr; cbi = nbi;
        }
    }

    // main loop: SCL stored outputs
#pragma unroll 2
    for (int s = 0; s < SCL; ++s) {
        const int t = t0 + s;
        const float pl = pin[0];
        const float th = pin[512];
        const float re = pin[1024];
        const float im = pin[1536];
        pin += 2048;
        const float om = 1.f - 1.f / (1.f + __expf(-pl));
        float sn, cs; __sincosf(th, &sn, &cs);
        float car = om * cs, cai = om * sn, cbr = re, cbi = im;
        if (t == 0) {
            // masked position: frozen at e_0[0]; seed all pipeline levels
#pragma unroll
            for (int k = 0; k < 13; ++k) { par[k] = car; pai[k] = cai; pbr[k] = cbr; pbi[k] = cbi; }
        } else {
#pragma unroll
            for (int k = 0; k < 13; ++k) {
                const float tar = par[k], tai = pai[k], tbr = pbr[k], tbi = pbi[k];
                par[k] = car; pai[k] = cai; pbr[k] = cbr; pbi[k] = cbi;
                const float nbr = car * tbr - cai * tbi + cbr;
                const float nbi = car * tbi + cai * tbr + cbi;
                if (k < 12) {
                    const float nar = car * tar - cai * tai;
                    const float nai = car * tai + cai * tar;
                    car = nar; cai = nai;
                }
                cbr = nbr; cbi = nbi;
            }
        }
        pout[(size_t)s * DD] = cbr;
    }
}

// ---------------------------------------------------------------- h_mean partials
__global__ __launch_bounds__(256) void hmean_kernel(const float* __restrict__ h_re,
                                                    float* __restrict__ hsum) {
    const int blk = blockIdx.x;          // 256 = 4b * 2dh * 32tc
    const int b = blk >> 6;
    const int dh = (blk >> 5) & 1;
    const int tc = blk & 31;
    const int d = dh * 256 + threadIdx.x;
    float s = 0.f;
    const float* p = h_re + ((size_t)(b * TT + tc * 128)) * DD + d;
    for (int t = 0; t < 128; ++t) s += p[(size_t)t * DD];
    atomicAdd(&hsum[b * DD + d], s);
}

// ---------------------------------------------------------------- top-16
__global__ __launch_bounds__(256) void topk_kernel(const float* __restrict__ ps,
                                                   int* __restrict__ idx_out) {
    __shared__ float vals[TT];
    __shared__ float rv[4];
    __shared__ int ri[4];
    const int b = blockIdx.x, tid = threadIdx.x;
    for (int i = tid; i < TT; i += 256) vals[i] = ps[b * TT + i];
    __syncthreads();
    for (int kk = 0; kk < 16; ++kk) {
        float bv = -1e30f; int bi = 0x7fffffff;
        for (int i = tid; i < TT; i += 256) {
            const float v = vals[i];
            if (v > bv || (v == bv && i < bi)) { bv = v; bi = i; }
        }
#pragma unroll
        for (int o = 32; o; o >>= 1) {
            const float ov = __shfl_down(bv, o);
            const int oi = __shfl_down(bi, o);
            if (ov > bv || (ov == bv && oi < bi)) { bv = ov; bi = oi; }
        }
        const int lane = tid & 63, wid = tid >> 6;
        if (!lane) { rv[wid] = bv; ri[wid] = bi; }
        __syncthreads();
        if (!tid) {
            float fbv = rv[0]; int fbi = ri[0];
            for (int w = 1; w < 4; ++w)
                if (rv[w] > fbv || (rv[w] == fbv && ri[w] < fbi)) { fbv = rv[w]; fbi = ri[w]; }
            idx_out[b * 16 + kk] = fbi;
            vals[fbi] = -1e30f;
        }
        __syncthreads();
    }
}

// ---------------------------------------------------------------- keys/values
__global__ __launch_bounds__(256) void kv_kernel(
    const float* __restrict__ h_re, const int* __restrict__ tki,
    const float* __restrict__ Wk, const float* __restrict__ Wkb,
    const float* __restrict__ Wv, const float* __restrict__ Wvb,
    float* __restrict__ keys, float* __restrict__ vals) {
    const int blk = blockIdx.x;
    const int b = blk >> 4, j = blk & 15;
    const int tid = threadIdx.x;
    __shared__ float hrow[512];
    const int row = tki[b * 16 + j];
    for (int i = tid; i < 512; i += 256)
        hrow[i] = h_re[((size_t)(b * TT + row)) * DD + i];
    __syncthreads();
    for (int n = tid; n < 512; n += 256) {
        float sk = Wkb[n], sv = Wvb[n];
        for (int k = 0; k < 512; ++k) {
            const float h = hrow[k];
            sk += h * Wk[(size_t)k * 512 + n];
            sv += h * Wv[(size_t)k * 512 + n];
        }
        keys[((size_t)(b * 16 + j)) * 512 + n] = sk;
        vals[((size_t)(b * 16 + j)) * 512 + n] = sv;
    }
}

// ---------------------------------------------------------------- query/gate/attn/out
__global__ __launch_bounds__(256) void attn_out_kernel(
    const float* __restrict__ hsum, const float* __restrict__ Wq,
    const float* __restrict__ Wqb, const float* __restrict__ gw,
    const float* __restrict__ gb, const float* __restrict__ keys,
    const float* __restrict__ vals, float* __restrict__ out1) {
    const int b = blockIdx.x, tid = threadIdx.x;
    const int lane = tid & 63, wid = tid >> 6;
    __shared__ float hm[512];
    __shared__ float q[512];
    __shared__ float sc[16];
    __shared__ float red[4];
    for (int d0 = tid; d0 < 512; d0 += 256)
        hm[d0] = hsum[b * 512 + d0] * (1.f / 4096.f);
    __syncthreads();
    for (int n = tid; n < 512; n += 256) {
        float s = Wqb[n];
        for (int k = 0; k < 512; ++k) s += hm[k] * Wq[(size_t)k * 512 + n];
        q[n] = s;
    }
    float gp = 0.f;
    for (int k = tid; k < 512; k += 256) gp += hm[k] * gw[k];
#pragma unroll
    for (int o = 32; o; o >>= 1) gp += __shfl_down(gp, o);
    if (!lane) red[wid] = gp;
    __syncthreads();   // q and red ready
    const float g = 1.f / (1.f + __expf(-(red[0] + red[1] + red[2] + red[3] + gb[0])));
    for (int kk = wid; kk < 16; kk += 4) {
        float sp = 0.f;
        const float* kr = keys + ((size_t)(b * 16 + kk)) * 512;
        for (int k2 = lane; k2 < 512; k2 += 64) sp += q[k2] * kr[k2];
#pragma unroll
        for (int o = 32; o; o >>= 1) sp += __shfl_down(sp, o);
        if (!lane) sc[kk] = sp * 0.04419417382415922f;  // 1/sqrt(512)
    }
    __syncthreads();
    float mx = sc[0];
#pragma unroll
    for (int kk = 1; kk < 16; ++kk) mx = fmaxf(mx, sc[kk]);
    float den = 0.f;
    float w16[16];
#pragma unroll
    for (int kk = 0; kk < 16; ++kk) { w16[kk] = __expf(sc[kk] - mx); den += w16[kk]; }
    const float rden = 1.f / den;
    for (int d0 = tid; d0 < 512; d0 += 256) {
        float co = 0.f;
#pragma unroll
        for (int kk = 0; kk < 16; ++kk)
            co += w16[kk] * vals[((size_t)(b * 16 + kk)) * 512 + d0];
        out1[b * 512 + d0] = hm[d0] + g * (co * rden);
    }
}

// ---------------------------------------------------------------- launch
extern "C" void kernel_launch(void* const* d_in, const int* in_sizes, int n_in,
                              void* d_out, int out_size, void* d_ws, size_t ws_size,
                              hipStream_t stream) {
    const float* x    = (const float*)d_in[0];
    const float* ln1g = (const float*)d_in[1];
    const float* ln1b = (const float*)d_in[2];
    const float* ln2g = (const float*)d_in[3];
    const float* ln2b = (const float*)d_in[4];
    const float* Wp_w = (const float*)d_in[5];
    const float* Wp_b = (const float*)d_in[6];
    const float* Wt_w = (const float*)d_in[7];
    const float* Wt_b = (const float*)d_in[8];
    const float* Wr_w = (const float*)d_in[9];
    const float* Wr_b = (const float*)d_in[10];
    const float* Wi_w = (const float*)d_in[11];
    const float* Wi_b = (const float*)d_in[12];
    const float* Wk_w = (const float*)d_in[13];
    const float* Wk_b = (const float*)d_in[14];
    const float* Wv_w = (const float*)d_in[15];
    const float* Wv_b = (const float*)d_in[16];
    const float* Wq_w = (const float*)d_in[17];
    const float* Wq_b = (const float*)d_in[18];
    const float* gw   = (const float*)d_in[19];
    const float* gb   = (const float*)d_in[20];
    const float* f1w  = (const float*)d_in[21];
    const float* f1b  = (const float*)d_in[22];
    const float* f2w  = (const float*)d_in[23];
    const float* f2b  = (const float*)d_in[24];

    char* wsp = (char*)d_ws;
    float* lin = (float*)wsp;                       // [M][2048] f32  (134 MB)
    char* p = wsp + (size_t)134217728;
    bf16* xn = (bf16*)p;     p += 16777216;         // [M][512] bf16
    float* h_re = (float*)p; p += 33554432;         // [M][512] f32
    bf16* hn = (bf16*)p;     p += 16777216;         // [M][512] bf16
    bf16* wcat = (bf16*)p;   p += 2097152;          // [2048][512] bf16 (Bt)
    bf16* f1bt = (bf16*)p;   p += 2097152;          // [2048][512] bf16
    bf16* f2bt = (bf16*)p;   p += 2097152;          // [512][2048] bf16
    float* bcat = (float*)p; p += 8192;             // [2048]
    float* ps = (float*)p;   p += 65536;            // [B][T]
    float* hsum = (float*)p; p += 8192;             // [B][512]
    int* tki = (int*)p;      p += 256;              // [B][16]
    float* keys = (float*)p; p += 131072;           // [B][16][512]
    float* valsb = (float*)p;                       // [B][16][512]
    bf16* act = (bf16*)lin;                         // FFN1 activations overlay lin
    float* out0 = (float*)d_out;
    float* out1 = (float*)d_out + OUT1_OFF;

    dim3 tb(32, 8);
    // weight packing (B^T bf16 layouts)
    transpose_bf16<<<dim3(16, 16), tb, 0, stream>>>(Wp_w, wcat + (size_t)0 * 512 * 512, 512, 512);
    transpose_bf16<<<dim3(16, 16), tb, 0, stream>>>(Wt_w, wcat + (size_t)1 * 512 * 512, 512, 512);
    transpose_bf16<<<dim3(16, 16), tb, 0, stream>>>(Wr_w, wcat + (size_t)2 * 512 * 512, 512, 512);
    transpose_bf16<<<dim3(16, 16), tb, 0, stream>>>(Wi_w, wcat + (size_t)3 * 512 * 512, 512, 512);
    transpose_bf16<<<dim3(64, 16), tb, 0, stream>>>(f1w, f1bt, 512, 2048);
    transpose_bf16<<<dim3(16, 64), tb, 0, stream>>>(f2w, f2bt, 2048, 512);
    pack_bias<<<8, 256, 0, stream>>>(Wp_b, Wt_b, Wr_b, Wi_b, bcat);

    // LN1 -> xn
    ln_kernel<<<4096, 256, 0, stream>>>(x, nullptr, ln1g, ln1b, xn);
    // fused 4-projection GEMM: lin = xn @ [Wp|Wt|Wr|Wi] + bias
    gemm_bt<0><<<2048, 256, 0, stream>>>(xn, wcat, bcat, lin, nullptr, nullptr, MM, 2048, 512);
    // p_scalar rows
    pscalar_kernel<<<4096, 256, 0, stream>>>(lin, ps);
    // 13-stage pipeline scan (transform fused) -> h_re
    scan_kernel<<<1024, 256, 0, stream>>>(lin, h_re);
    // h_mean partial sums
    zero_kernel<<<8, 256, 0, stream>>>(hsum, 2048);
    hmean_kernel<<<256, 256, 0, stream>>>(h_re, hsum);
    // cache path
    topk_kernel<<<4, 256, 0, stream>>>(ps, tki);
    kv_kernel<<<64, 256, 0, stream>>>(h_re, tki, Wk_w, Wk_b, Wv_w, Wv_b, keys, valsb);
    attn_out_kernel<<<4, 256, 0, stream>>>(hsum, Wq_w, Wq_b, gw, gb, keys, valsb, out1);
    // FFN path
    ln_kernel<<<4096, 256, 0, stream>>>(h_re, x, ln2g, ln2b, hn);
    gemm_bt<1><<<2048, 256, 0, stream>>>(hn, f1bt, f1b, act, nullptr, nullptr, MM, 2048, 512);
    gemm_bt<2><<<512, 256, 0, stream>>>(act, f2bt, f2b, out0, h_re, x, MM, 512, 2048);
}